// Round 6
// baseline (2888.662 us; speedup 1.0000x reference)
//
#include <hip/hip_runtime.h>
#include <hip/hip_cooperative_groups.h>
#include <cstddef>
#include <cstdint>

namespace cg = cooperative_groups;

#define N_PTS 4096
#define DIMK 1024

typedef _Float16 half8 __attribute__((ext_vector_type(8)));
typedef float floatx4 __attribute__((ext_vector_type(4)));

static constexpr float S_SCALE = 144.26950408889634f;   // 100*log2(e)
static constexpr float TWO_S   = 288.53900817779268f;   // 200*log2(e)
static constexpr float NEG_BIG = -3.4e38f;

// ws layout (bytes):
//   [0, 16K)        fvec (f~2s, shifted/gauged)
//   [16K, 32K)      gvec
//   [32K, +32M)     Ah, Al, Bh, Bl (fp16 hi/lo splits; 8 MB each)
//   [then, +64M)    DT (transposed D for coalesced col-sweeps)
// Shifted/gauged coords: D2 = -2*S*x.y ; f2s_0 = S*(1024 - ||x_i||^2);
// f2s+g2s-D2 equals the reference's f+g-C exactly (gauge cancels).
// Round-6: round-4 DT structure restored; 60 sweeps + final fused into one
// cooperative kernel (grid.sync between half-sweeps) to kill launch gaps.

__device__ __forceinline__ float4 f4max(float4 a, float4 b) {
  return make_float4(fmaxf(a.x, b.x), fmaxf(a.y, b.y), fmaxf(a.z, b.z), fmaxf(a.w, b.w));
}
__device__ __forceinline__ void msmerge(float4& M, float4& S, const float4 M2, const float4 S2) {
  float4 Mn = f4max(M, M2);
  S.x = S.x * exp2f(M.x - Mn.x) + S2.x * exp2f(M2.x - Mn.x);
  S.y = S.y * exp2f(M.y - Mn.y) + S2.y * exp2f(M2.y - Mn.y);
  S.z = S.z * exp2f(M.z - Mn.z) + S2.z * exp2f(M2.z - Mn.z);
  S.w = S.w * exp2f(M.w - Mn.w) + S2.w * exp2f(M2.w - Mn.w);
  M = Mn;
}

// ---------------- prep: f~2s init = S*(1024 - ||Xs_i||^2) ----------------
__global__ __launch_bounds__(256) void k_prep(const float* __restrict__ Xs,
                                              float* __restrict__ fvec) {
  int row  = blockIdx.x * 4 + (threadIdx.x >> 6);
  int lane = threadIdx.x & 63;
  const float* src = Xs + (size_t)row * DIMK;
  float s = 0.f;
#pragma unroll
  for (int r = 0; r < 4; ++r) {
    float4 a = *(const float4*)(src + lane * 4 + r * 256);
    s += a.x * a.x + a.y * a.y + a.z * a.z + a.w * a.w;
  }
#pragma unroll
  for (int off = 32; off; off >>= 1) s += __shfl_xor(s, off);
  if (lane == 0) fvec[row] = (1024.0f - s) * S_SCALE;
}

// ---------------- convert: fp32 -> (hi, lo) fp16 split ----------------
__global__ __launch_bounds__(256) void k_convert(const float* __restrict__ X,
                                                 _Float16* __restrict__ H,
                                                 _Float16* __restrict__ L) {
  size_t i8 = ((size_t)blockIdx.x * 256 + threadIdx.x) * 8;
  float4 a = *(const float4*)(X + i8);
  float4 b = *(const float4*)(X + i8 + 4);
  float v[8] = {a.x, a.y, a.z, a.w, b.x, b.y, b.z, b.w};
  half8 h, l;
#pragma unroll
  for (int q = 0; q < 8; ++q) {
    _Float16 hh = (_Float16)v[q];
    h[q] = hh;
    l[q] = (_Float16)(v[q] - (float)hh);
  }
  *(half8*)(H + i8) = h;
  *(half8*)(L + i8) = l;
}

// ---------------- MFMA split-fp16 GEMM: D = -2S * (Ah+Al).(Bh+Bl)^T ----------------
// 128x128 tile, BK=32, 4 waves as 2x2, each wave 4x4 subtiles of 16x16x32.
// dot = hh + hl + lh (lo*lo dropped: < 2^-22 relative). Writes D and DT.
__global__ __launch_bounds__(256) void k_gemm_mfma(const _Float16* __restrict__ Ah,
                                                   const _Float16* __restrict__ Al,
                                                   const _Float16* __restrict__ Bh,
                                                   const _Float16* __restrict__ Bl,
                                                   float* __restrict__ D,
                                                   float* __restrict__ DT) {
  __shared__ __align__(16) _Float16 Ahs[128 * 32];
  __shared__ __align__(16) _Float16 Als[128 * 32];
  __shared__ __align__(16) _Float16 Bhs[128 * 32];
  __shared__ __align__(16) _Float16 Bls[128 * 32];
  const int t    = threadIdx.x;
  const int lane = t & 63, wave = t >> 6;
  const int wm = wave >> 1, wn = wave & 1;
  const int lm = lane & 15, q = lane >> 4;
  const int row0 = blockIdx.y * 128, col0 = blockIdx.x * 128;

  floatx4 acc[4][4];
#pragma unroll
  for (int i = 0; i < 4; ++i)
#pragma unroll
    for (int j = 0; j < 4; ++j) acc[i][j] = (floatx4){0.f, 0.f, 0.f, 0.f};

  const int r0 = t >> 2, p0 = t & 3;
  const int r1 = 64 + r0;

  for (int k0 = 0; k0 < DIMK; k0 += 32) {
    size_t ga0 = (size_t)(row0 + r0) * DIMK + k0 + p0 * 8;
    size_t ga1 = (size_t)(row0 + r1) * DIMK + k0 + p0 * 8;
    size_t gb0 = (size_t)(col0 + r0) * DIMK + k0 + p0 * 8;
    size_t gb1 = (size_t)(col0 + r1) * DIMK + k0 + p0 * 8;
    half8 vah0 = *(const half8*)(Ah + ga0);
    half8 vah1 = *(const half8*)(Ah + ga1);
    half8 val0 = *(const half8*)(Al + ga0);
    half8 val1 = *(const half8*)(Al + ga1);
    half8 vbh0 = *(const half8*)(Bh + gb0);
    half8 vbh1 = *(const half8*)(Bh + gb1);
    half8 vbl0 = *(const half8*)(Bl + gb0);
    half8 vbl1 = *(const half8*)(Bl + gb1);
    __syncthreads();
    ((half8*)Ahs)[t] = vah0; ((half8*)Ahs)[t + 256] = vah1;
    ((half8*)Als)[t] = val0; ((half8*)Als)[t + 256] = val1;
    ((half8*)Bhs)[t] = vbh0; ((half8*)Bhs)[t + 256] = vbh1;
    ((half8*)Bls)[t] = vbl0; ((half8*)Bls)[t + 256] = vbl1;
    __syncthreads();

    half8 afh[4], afl[4], bfh[4], bfl[4];
#pragma unroll
    for (int i = 0; i < 4; ++i) {
      int ar = (wm * 64 + i * 16 + lm) * 32 + q * 8;
      int br = (wn * 64 + i * 16 + lm) * 32 + q * 8;
      afh[i] = *(const half8*)(Ahs + ar);
      afl[i] = *(const half8*)(Als + ar);
      bfh[i] = *(const half8*)(Bhs + br);
      bfl[i] = *(const half8*)(Bls + br);
    }
#pragma unroll
    for (int i = 0; i < 4; ++i)
#pragma unroll
      for (int j = 0; j < 4; ++j) {
        acc[i][j] = __builtin_amdgcn_mfma_f32_16x16x32_f16(afh[i], bfh[j], acc[i][j], 0, 0, 0);
        acc[i][j] = __builtin_amdgcn_mfma_f32_16x16x32_f16(afh[i], bfl[j], acc[i][j], 0, 0, 0);
        acc[i][j] = __builtin_amdgcn_mfma_f32_16x16x32_f16(afl[i], bfh[j], acc[i][j], 0, 0, 0);
      }
  }

  // epilogue: C/D layout col=lane&15, row=quad*4+reg
#pragma unroll
  for (int i = 0; i < 4; ++i) {
    int mbase = row0 + wm * 64 + i * 16 + q * 4;
#pragma unroll
    for (int j = 0; j < 4; ++j) {
      int n = col0 + wn * 64 + j * 16 + lm;
      float vals[4];
#pragma unroll
      for (int r = 0; r < 4; ++r) {
        float vv = -TWO_S * acc[i][j][r];
        vals[r] = vv;
        D[(size_t)(mbase + r) * N_PTS + n] = vv;
      }
      if (DT) *(float4*)(DT + (size_t)n * N_PTS + mbase) = *(float4*)vals;
    }
  }
}

// ---------------- fp32 fallback GEMM (ws too small for halves) ----------------
__global__ __launch_bounds__(256) void k_gemm(const float* __restrict__ A,
                                              const float* __restrict__ B,
                                              float* __restrict__ D) {
  __shared__ float As[16][132];
  __shared__ float Bs[16][132];
  const int t  = threadIdx.x;
  const int tx = t & 15, ty = t >> 4;
  const int row0 = blockIdx.y * 128, col0 = blockIdx.x * 128;
  float acc[8][8];
#pragma unroll
  for (int i = 0; i < 8; ++i)
#pragma unroll
    for (int j = 0; j < 8; ++j) acc[i][j] = 0.f;
  for (int k0 = 0; k0 < DIMK; k0 += 16) {
#pragma unroll
    for (int s2 = 0; s2 < 2; ++s2) {
      int f4i = t + s2 * 256;
      int r   = f4i >> 2;
      int kp  = (f4i & 3) << 2;
      float4 a4 = *(const float4*)(A + (size_t)(row0 + r) * DIMK + k0 + kp);
      float4 b4 = *(const float4*)(B + (size_t)(col0 + r) * DIMK + k0 + kp);
      As[kp + 0][r] = a4.x; As[kp + 1][r] = a4.y; As[kp + 2][r] = a4.z; As[kp + 3][r] = a4.w;
      Bs[kp + 0][r] = b4.x; Bs[kp + 1][r] = b4.y; Bs[kp + 2][r] = b4.z; Bs[kp + 3][r] = b4.w;
    }
    __syncthreads();
#pragma unroll
    for (int kk = 0; kk < 16; ++kk) {
      float a[8], b[8];
      *(float4*)(a)     = *(const float4*)(&As[kk][ty * 4]);
      *(float4*)(a + 4) = *(const float4*)(&As[kk][64 + ty * 4]);
      *(float4*)(b)     = *(const float4*)(&Bs[kk][tx * 4]);
      *(float4*)(b + 4) = *(const float4*)(&Bs[kk][64 + tx * 4]);
#pragma unroll
      for (int i = 0; i < 8; ++i)
#pragma unroll
        for (int j = 0; j < 8; ++j) acc[i][j] = fmaf(a[i], b[j], acc[i][j]);
    }
    __syncthreads();
  }
#pragma unroll
  for (int i = 0; i < 8; ++i) {
    int r = row0 + ((i < 4) ? (ty * 4 + i) : (64 + ty * 4 + (i - 4)));
    float* out = D + (size_t)r * N_PTS + col0;
    float4 o1, o2;
    o1.x = -TWO_S * acc[i][0]; o1.y = -TWO_S * acc[i][1];
    o1.z = -TWO_S * acc[i][2]; o1.w = -TWO_S * acc[i][3];
    o2.x = -TWO_S * acc[i][4]; o2.y = -TWO_S * acc[i][5];
    o2.z = -TWO_S * acc[i][6]; o2.w = -TWO_S * acc[i][7];
    *(float4*)(out + tx * 4)      = o1;
    *(float4*)(out + 64 + tx * 4) = o2;
  }
}

// ---------------- shared row-LSE over 4096 entries (one wave per row) ----------------
// returns 12 - log2 sum_j 2^(vin[j] - rowp[j]); numerics identical to round-4 k_sweep.
__device__ __forceinline__ float lse_row4096(const float* __restrict__ rowp,
                                             const float* __restrict__ vin,
                                             int l) {
  float4 dv[16], gv[16];
#pragma unroll
  for (int k = 0; k < 16; ++k) dv[k] = *(const float4*)(rowp + l * 4 + k * 256);
#pragma unroll
  for (int k = 0; k < 16; ++k) gv[k] = *(const float4*)(vin + l * 4 + k * 256);
  float M = NEG_BIG, S = 0.f;
#pragma unroll
  for (int c = 0; c < 4; ++c) {
    float v[16];
#pragma unroll
    for (int q = 0; q < 4; ++q) {
      float4 d = dv[c * 4 + q], g = gv[c * 4 + q];
      v[q * 4 + 0] = g.x - d.x; v[q * 4 + 1] = g.y - d.y;
      v[q * 4 + 2] = g.z - d.z; v[q * 4 + 3] = g.w - d.w;
    }
    float Mc = v[0];
#pragma unroll
    for (int q = 1; q < 16; ++q) Mc = fmaxf(Mc, v[q]);
    float Mn = fmaxf(M, Mc);
    float s = S * exp2f(M - Mn);
#pragma unroll
    for (int q = 0; q < 16; ++q) s += exp2f(v[q] - Mn);
    M = Mn; S = s;
  }
#pragma unroll
  for (int off = 32; off; off >>= 1) {
    float M2 = __shfl_xor(M, off);
    float S2 = __shfl_xor(S, off);
    float Mn = fmaxf(M, M2);
    S = S * exp2f(M - Mn) + S2 * exp2f(M2 - Mn);
    M = Mn;
  }
  return 12.0f - M - log2f(S);
}

// ---------------- cooperative iteration loop + final (one dispatch) ----------------
// grid 256 x 512 (8 waves/block, 1 block/CU). Wave w owns rows/cols
// {blk*16 + 2w, +1}. 60 grid.sync()s between half-sweeps; final P fused.
__global__ __launch_bounds__(512, 2) void k_loop(float* __restrict__ D,
                                                 const float* __restrict__ DT,
                                                 float* __restrict__ fvec,
                                                 float* __restrict__ gvec) {
  cg::grid_group grid = cg::this_grid();
  const int t = threadIdx.x;
  const int l = t & 63, w = t >> 6;
  const int base = blockIdx.x * 16 + w * 2;

  for (int it = 0; it < 30; ++it) {
#pragma unroll
    for (int h = 0; h < 2; ++h) {      // col phase: g = T(f), streams DT
      int c = base + h;
      float g = lse_row4096(DT + (size_t)c * N_PTS, fvec, l);
      if (l == 0) gvec[c] = g;
    }
    grid.sync();
#pragma unroll
    for (int h = 0; h < 2; ++h) {      // row phase: f = T(g), streams D
      int r = base + h;
      float f = lse_row4096(D + (size_t)r * N_PTS, gvec, l);
      if (l == 0) fvec[r] = f;
    }
    grid.sync();
  }
  // final: P = exp2(0.1*(f_i + g_j - D_ij)) in place
#pragma unroll
  for (int h = 0; h < 2; ++h) {
    int r = base + h;
    float fi = fvec[r];
    float* rp = D + (size_t)r * N_PTS;
#pragma unroll 4
    for (int k = 0; k < 16; ++k) {
      int j = l * 4 + k * 256;
      float4 d  = *(const float4*)(rp + j);
      float4 g4 = *(const float4*)(gvec + j);
      d.x = exp2f(0.1f * (fi + g4.x - d.x));
      d.y = exp2f(0.1f * (fi + g4.y - d.y));
      d.z = exp2f(0.1f * (fi + g4.z - d.z));
      d.w = exp2f(0.1f * (fi + g4.w - d.w));
      *(float4*)(rp + j) = d;
    }
  }
}

// ---------------- fallback per-launch sweeps (ws too small for DT) ----------------
__global__ __launch_bounds__(256) void k_sweep(const float* __restrict__ Mrow,
                                               const float* __restrict__ vin,
                                               float* __restrict__ vout) {
  const int l = threadIdx.x & 63;
  const int row = blockIdx.x * 4 + (threadIdx.x >> 6);
  float r = lse_row4096(Mrow + (size_t)row * N_PTS, vin, l);
  if (l == 0) vout[row] = r;
}

__global__ __launch_bounds__(1024) void k_colpass(const float* __restrict__ D,
                                                  const float* __restrict__ fvec,
                                                  float* __restrict__ gvec) {
  __shared__ float fs[N_PTS];
  __shared__ float4 MS[16][4][2];
  const int t = threadIdx.x;
  *(float4*)(fs + t * 4) = *(const float4*)(fvec + t * 4);
  __syncthreads();
  const int c4 = t & 3;
  const int rp = t >> 2;
  const float* base = D + blockIdx.x * 16 + c4 * 4;
  float4 M = make_float4(NEG_BIG, NEG_BIG, NEG_BIG, NEG_BIG);
  float4 S = make_float4(0.f, 0.f, 0.f, 0.f);
#pragma unroll
  for (int h = 0; h < 2; ++h) {
    float4 v[8];
#pragma unroll
    for (int qq = 0; qq < 8; ++qq) {
      int r = rp + (h * 8 + qq) * 256;
      float4 d = *(const float4*)(base + (size_t)r * N_PTS);
      float fr = fs[r];
      v[qq] = make_float4(fr - d.x, fr - d.y, fr - d.z, fr - d.w);
    }
    float4 Mc = f4max(f4max(f4max(v[0], v[1]), f4max(v[2], v[3])),
                      f4max(f4max(v[4], v[5]), f4max(v[6], v[7])));
    float4 Mn = f4max(M, Mc);
    float4 s;
    s.x = S.x * exp2f(M.x - Mn.x);
    s.y = S.y * exp2f(M.y - Mn.y);
    s.z = S.z * exp2f(M.z - Mn.z);
    s.w = S.w * exp2f(M.w - Mn.w);
#pragma unroll
    for (int qq = 0; qq < 8; ++qq) {
      s.x += exp2f(v[qq].x - Mn.x);
      s.y += exp2f(v[qq].y - Mn.y);
      s.z += exp2f(v[qq].z - Mn.z);
      s.w += exp2f(v[qq].w - Mn.w);
    }
    M = Mn; S = s;
  }
#pragma unroll
  for (int off = 4; off <= 32; off <<= 1) {
    float4 M2, S2;
    M2.x = __shfl_xor(M.x, off); M2.y = __shfl_xor(M.y, off);
    M2.z = __shfl_xor(M.z, off); M2.w = __shfl_xor(M.w, off);
    S2.x = __shfl_xor(S.x, off); S2.y = __shfl_xor(S.y, off);
    S2.z = __shfl_xor(S.z, off); S2.w = __shfl_xor(S.w, off);
    msmerge(M, S, M2, S2);
  }
  const int wv = t >> 6, l = t & 63;
  if (l < 4) { MS[wv][l][0] = M; MS[wv][l][1] = S; }
  __syncthreads();
  if (t < 4) {
    float4 M0 = MS[0][t][0], S0 = MS[0][t][1];
#pragma unroll
    for (int w = 1; w < 16; ++w) msmerge(M0, S0, MS[w][t][0], MS[w][t][1]);
    float4 g;
    g.x = 12.0f - M0.x - log2f(S0.x);
    g.y = 12.0f - M0.y - log2f(S0.y);
    g.z = 12.0f - M0.z - log2f(S0.z);
    g.w = 12.0f - M0.w - log2f(S0.w);
    *(float4*)(gvec + blockIdx.x * 16 + t * 4) = g;
  }
}

__global__ __launch_bounds__(256) void k_final(float* __restrict__ D,
                                               const float* __restrict__ fvec,
                                               const float* __restrict__ gvec) {
  size_t idx = ((size_t)blockIdx.x * 256 + threadIdx.x) * 8;
  int i = (int)(idx >> 12);
  int j = (int)(idx & (N_PTS - 1));
  float fi = fvec[i];
#pragma unroll
  for (int h = 0; h < 2; ++h) {
    float4 d  = *(float4*)(D + idx + h * 4);
    float4 g4 = *(const float4*)(gvec + j + h * 4);
    d.x = exp2f(0.1f * (fi + g4.x - d.x));
    d.y = exp2f(0.1f * (fi + g4.y - d.y));
    d.z = exp2f(0.1f * (fi + g4.z - d.z));
    d.w = exp2f(0.1f * (fi + g4.w - d.w));
    *(float4*)(D + idx + h * 4) = d;
  }
}

extern "C" void kernel_launch(void* const* d_in, const int* in_sizes, int n_in,
                              void* d_out, int out_size, void* d_ws, size_t ws_size,
                              hipStream_t stream) {
  const float* Xs = (const float*)d_in[0];
  const float* Xt = (const float*)d_in[1];
  float* D   = (float*)d_out;
  char* wsb  = (char*)d_ws;
  float* fvec = (float*)wsb;
  float* gvec = fvec + N_PTS;

  const size_t halfElems = (size_t)N_PTS * DIMK;
  const size_t offHalves = 32768;
  _Float16* Ah = (_Float16*)(wsb + offHalves);
  _Float16* Al = Ah + halfElems;
  _Float16* Bh = Al + halfElems;
  _Float16* Bl = Bh + halfElems;
  float* DT = (float*)(wsb + offHalves + 4 * halfElems * sizeof(_Float16));
  const size_t needHalves = offHalves + 4 * halfElems * sizeof(_Float16);          // ~32.03 MB
  const size_t needFull   = needHalves + (size_t)N_PTS * N_PTS * sizeof(float);    // +64 MB
  const bool haveH = ws_size >= needHalves;
  const bool haveT = ws_size >= needFull;   // confirmed true in rounds 4/5 (ws >= 96 MB)

  k_prep<<<1024, 256, 0, stream>>>(Xs, fvec);
  if (haveH) {
    k_convert<<<2048, 256, 0, stream>>>(Xs, Ah, Al);
    k_convert<<<2048, 256, 0, stream>>>(Xt, Bh, Bl);
    k_gemm_mfma<<<dim3(32, 32), 256, 0, stream>>>(Ah, Al, Bh, Bl, D, haveT ? DT : nullptr);
  } else {
    k_gemm<<<dim3(32, 32), 256, 0, stream>>>(Xs, Xt, D);
  }

  if (haveT) {
    void* args[] = {(void*)&D, (void*)&DT, (void*)&fvec, (void*)&gvec};
    hipLaunchCooperativeKernel((const void*)k_loop, dim3(256), dim3(512), args, 0, stream);
  } else {
    for (int it = 0; it < 30; ++it) {
      k_colpass<<<256, 1024, 0, stream>>>(D, fvec, gvec);
      k_sweep<<<1024, 256, 0, stream>>>(D, gvec, fvec);
    }
    k_final<<<8192, 256, 0, stream>>>(D, fvec, gvec);
  }
}

// Round 7
// 1791.265 us; speedup vs baseline: 1.6126x; 1.6126x over previous
//
#include <hip/hip_runtime.h>
#include <cstddef>
#include <cstdint>

#define N_PTS 4096
#define DIMK 1024

typedef _Float16 half8 __attribute__((ext_vector_type(8)));
typedef float floatx4 __attribute__((ext_vector_type(4)));

static constexpr float S_SCALE = 144.26950408889634f;   // 100*log2(e)
static constexpr float TWO_S   = 288.53900817779268f;   // 200*log2(e)
static constexpr float NEG_BIG = -3.4e38f;

// ws layout (bytes):
//   [0, 16K)        fvec   [16K, 32K) gvec      (loop-mutable: bypass ops only)
//   [32K, +32M)     Ah, Al, Bh, Bl (fp16 hi/lo splits)
//   [then, +64M)    DT
//   [then, +1K)     barrier counter (monotone)
// Round-7: round-6 fused loop kept, cg::grid.sync replaced by fence-free
// monotone atomic barrier; fvec/gvec cross XCDs via coherence-point (L3)
// bypass ops; D/DT stay normally cached (read-only during loop).

__device__ __forceinline__ float4 f4max(float4 a, float4 b) {
  return make_float4(fmaxf(a.x, b.x), fmaxf(a.y, b.y), fmaxf(a.z, b.z), fmaxf(a.w, b.w));
}
__device__ __forceinline__ void msmerge(float4& M, float4& S, const float4 M2, const float4 S2) {
  float4 Mn = f4max(M, M2);
  S.x = S.x * exp2f(M.x - Mn.x) + S2.x * exp2f(M2.x - Mn.x);
  S.y = S.y * exp2f(M.y - Mn.y) + S2.y * exp2f(M2.y - Mn.y);
  S.z = S.z * exp2f(M.z - Mn.z) + S2.z * exp2f(M2.z - Mn.z);
  S.w = S.w * exp2f(M.w - Mn.w) + S2.w * exp2f(M2.w - Mn.w);
  M = Mn;
}

// ---------------- prep: f~2s init = S*(1024 - ||Xs_i||^2); zero barrier ----------------
__global__ __launch_bounds__(256) void k_prep(const float* __restrict__ Xs,
                                              float* __restrict__ fvec,
                                              unsigned* __restrict__ bar) {
  if (blockIdx.x == 0 && threadIdx.x < 16 && bar) bar[threadIdx.x] = 0u;
  int row  = blockIdx.x * 4 + (threadIdx.x >> 6);
  int lane = threadIdx.x & 63;
  const float* src = Xs + (size_t)row * DIMK;
  float s = 0.f;
#pragma unroll
  for (int r = 0; r < 4; ++r) {
    float4 a = *(const float4*)(src + lane * 4 + r * 256);
    s += a.x * a.x + a.y * a.y + a.z * a.z + a.w * a.w;
  }
#pragma unroll
  for (int off = 32; off; off >>= 1) s += __shfl_xor(s, off);
  if (lane == 0) fvec[row] = (1024.0f - s) * S_SCALE;
}

// ---------------- convert: fp32 -> (hi, lo) fp16 split ----------------
__global__ __launch_bounds__(256) void k_convert(const float* __restrict__ X,
                                                 _Float16* __restrict__ H,
                                                 _Float16* __restrict__ L) {
  size_t i8 = ((size_t)blockIdx.x * 256 + threadIdx.x) * 8;
  float4 a = *(const float4*)(X + i8);
  float4 b = *(const float4*)(X + i8 + 4);
  float v[8] = {a.x, a.y, a.z, a.w, b.x, b.y, b.z, b.w};
  half8 h, l;
#pragma unroll
  for (int q = 0; q < 8; ++q) {
    _Float16 hh = (_Float16)v[q];
    h[q] = hh;
    l[q] = (_Float16)(v[q] - (float)hh);
  }
  *(half8*)(H + i8) = h;
  *(half8*)(L + i8) = l;
}

// ---------------- MFMA split-fp16 GEMM: D = -2S * (Ah+Al).(Bh+Bl)^T ----------------
__global__ __launch_bounds__(256) void k_gemm_mfma(const _Float16* __restrict__ Ah,
                                                   const _Float16* __restrict__ Al,
                                                   const _Float16* __restrict__ Bh,
                                                   const _Float16* __restrict__ Bl,
                                                   float* __restrict__ D,
                                                   float* __restrict__ DT) {
  __shared__ __align__(16) _Float16 Ahs[128 * 32];
  __shared__ __align__(16) _Float16 Als[128 * 32];
  __shared__ __align__(16) _Float16 Bhs[128 * 32];
  __shared__ __align__(16) _Float16 Bls[128 * 32];
  const int t    = threadIdx.x;
  const int lane = t & 63, wave = t >> 6;
  const int wm = wave >> 1, wn = wave & 1;
  const int lm = lane & 15, q = lane >> 4;
  const int row0 = blockIdx.y * 128, col0 = blockIdx.x * 128;

  floatx4 acc[4][4];
#pragma unroll
  for (int i = 0; i < 4; ++i)
#pragma unroll
    for (int j = 0; j < 4; ++j) acc[i][j] = (floatx4){0.f, 0.f, 0.f, 0.f};

  const int r0 = t >> 2, p0 = t & 3;
  const int r1 = 64 + r0;

  for (int k0 = 0; k0 < DIMK; k0 += 32) {
    size_t ga0 = (size_t)(row0 + r0) * DIMK + k0 + p0 * 8;
    size_t ga1 = (size_t)(row0 + r1) * DIMK + k0 + p0 * 8;
    size_t gb0 = (size_t)(col0 + r0) * DIMK + k0 + p0 * 8;
    size_t gb1 = (size_t)(col0 + r1) * DIMK + k0 + p0 * 8;
    half8 vah0 = *(const half8*)(Ah + ga0);
    half8 vah1 = *(const half8*)(Ah + ga1);
    half8 val0 = *(const half8*)(Al + ga0);
    half8 val1 = *(const half8*)(Al + ga1);
    half8 vbh0 = *(const half8*)(Bh + gb0);
    half8 vbh1 = *(const half8*)(Bh + gb1);
    half8 vbl0 = *(const half8*)(Bl + gb0);
    half8 vbl1 = *(const half8*)(Bl + gb1);
    __syncthreads();
    ((half8*)Ahs)[t] = vah0; ((half8*)Ahs)[t + 256] = vah1;
    ((half8*)Als)[t] = val0; ((half8*)Als)[t + 256] = val1;
    ((half8*)Bhs)[t] = vbh0; ((half8*)Bhs)[t + 256] = vbh1;
    ((half8*)Bls)[t] = vbl0; ((half8*)Bls)[t + 256] = vbl1;
    __syncthreads();

    half8 afh[4], afl[4], bfh[4], bfl[4];
#pragma unroll
    for (int i = 0; i < 4; ++i) {
      int ar = (wm * 64 + i * 16 + lm) * 32 + q * 8;
      int br = (wn * 64 + i * 16 + lm) * 32 + q * 8;
      afh[i] = *(const half8*)(Ahs + ar);
      afl[i] = *(const half8*)(Als + ar);
      bfh[i] = *(const half8*)(Bhs + br);
      bfl[i] = *(const half8*)(Bls + br);
    }
#pragma unroll
    for (int i = 0; i < 4; ++i)
#pragma unroll
      for (int j = 0; j < 4; ++j) {
        acc[i][j] = __builtin_amdgcn_mfma_f32_16x16x32_f16(afh[i], bfh[j], acc[i][j], 0, 0, 0);
        acc[i][j] = __builtin_amdgcn_mfma_f32_16x16x32_f16(afh[i], bfl[j], acc[i][j], 0, 0, 0);
        acc[i][j] = __builtin_amdgcn_mfma_f32_16x16x32_f16(afl[i], bfh[j], acc[i][j], 0, 0, 0);
      }
  }

#pragma unroll
  for (int i = 0; i < 4; ++i) {
    int mbase = row0 + wm * 64 + i * 16 + q * 4;
#pragma unroll
    for (int j = 0; j < 4; ++j) {
      int n = col0 + wn * 64 + j * 16 + lm;
      float vals[4];
#pragma unroll
      for (int r = 0; r < 4; ++r) {
        float vv = -TWO_S * acc[i][j][r];
        vals[r] = vv;
        D[(size_t)(mbase + r) * N_PTS + n] = vv;
      }
      if (DT) *(float4*)(DT + (size_t)n * N_PTS + mbase) = *(float4*)vals;
    }
  }
}

// ---------------- shared row-LSE (vin from global) ----------------
__device__ __forceinline__ float lse_row4096(const float* __restrict__ rowp,
                                             const float* __restrict__ vin,
                                             int l) {
  float4 dv[16], gv[16];
#pragma unroll
  for (int k = 0; k < 16; ++k) dv[k] = *(const float4*)(rowp + l * 4 + k * 256);
#pragma unroll
  for (int k = 0; k < 16; ++k) gv[k] = *(const float4*)(vin + l * 4 + k * 256);
  float M = NEG_BIG, S = 0.f;
#pragma unroll
  for (int c = 0; c < 4; ++c) {
    float v[16];
#pragma unroll
    for (int q = 0; q < 4; ++q) {
      float4 d = dv[c * 4 + q], g = gv[c * 4 + q];
      v[q * 4 + 0] = g.x - d.x; v[q * 4 + 1] = g.y - d.y;
      v[q * 4 + 2] = g.z - d.z; v[q * 4 + 3] = g.w - d.w;
    }
    float Mc = v[0];
#pragma unroll
    for (int q = 1; q < 16; ++q) Mc = fmaxf(Mc, v[q]);
    float Mn = fmaxf(M, Mc);
    float s = S * exp2f(M - Mn);
#pragma unroll
    for (int q = 0; q < 16; ++q) s += exp2f(v[q] - Mn);
    M = Mn; S = s;
  }
#pragma unroll
  for (int off = 32; off; off >>= 1) {
    float M2 = __shfl_xor(M, off);
    float S2 = __shfl_xor(S, off);
    float Mn = fmaxf(M, M2);
    S = S * exp2f(M - Mn) + S2 * exp2f(M2 - Mn);
    M = Mn;
  }
  return 12.0f - M - log2f(S);
}

// ---------------- row-LSE with vin staged in LDS (same numeric order) ----------------
__device__ __forceinline__ float lse_row_lds(const float* __restrict__ rowp,
                                             const float* __restrict__ vs,
                                             int l) {
  float4 dv[16];
#pragma unroll
  for (int k = 0; k < 16; ++k) dv[k] = *(const float4*)(rowp + l * 4 + k * 256);
  float M = NEG_BIG, S = 0.f;
#pragma unroll
  for (int c = 0; c < 4; ++c) {
    float v[16];
#pragma unroll
    for (int q = 0; q < 4; ++q) {
      float4 d = dv[c * 4 + q];
      const float* gp = vs + l * 4 + (c * 4 + q) * 256;
      v[q * 4 + 0] = gp[0] - d.x; v[q * 4 + 1] = gp[1] - d.y;
      v[q * 4 + 2] = gp[2] - d.z; v[q * 4 + 3] = gp[3] - d.w;
    }
    float Mc = v[0];
#pragma unroll
    for (int q = 1; q < 16; ++q) Mc = fmaxf(Mc, v[q]);
    float Mn = fmaxf(M, Mc);
    float s = S * exp2f(M - Mn);
#pragma unroll
    for (int q = 0; q < 16; ++q) s += exp2f(v[q] - Mn);
    M = Mn; S = s;
  }
#pragma unroll
  for (int off = 32; off; off >>= 1) {
    float M2 = __shfl_xor(M, off);
    float S2 = __shfl_xor(S, off);
    float Mn = fmaxf(M, M2);
    S = S * exp2f(M - Mn) + S2 * exp2f(M2 - Mn);
    M = Mn;
  }
  return 12.0f - M - log2f(S);
}

// stage 4096 floats from coherence point (bypass L1/L2) into LDS
__device__ __forceinline__ void stage_vec(float* __restrict__ vs,
                                          const float* __restrict__ src, int t) {
  floatx4 v0, v1, v2, v3;
  const float* p0 = src + t * 4;
  const float* p1 = src + 1024 + t * 4;
  const float* p2 = src + 2048 + t * 4;
  const float* p3 = src + 3072 + t * 4;
  asm volatile(
      "global_load_dwordx4 %0, %4, off sc0 sc1\n\t"
      "global_load_dwordx4 %1, %5, off sc0 sc1\n\t"
      "global_load_dwordx4 %2, %6, off sc0 sc1\n\t"
      "global_load_dwordx4 %3, %7, off sc0 sc1\n\t"
      "s_waitcnt vmcnt(0)"
      : "=&v"(v0), "=&v"(v1), "=&v"(v2), "=&v"(v3)
      : "v"(p0), "v"(p1), "v"(p2), "v"(p3)
      : "memory");
  *(floatx4*)(vs + t * 4) = v0;
  *(floatx4*)(vs + 1024 + t * 4) = v1;
  *(floatx4*)(vs + 2048 + t * 4) = v2;
  *(floatx4*)(vs + 3072 + t * 4) = v3;
}

// fence-free monotone grid barrier: one relaxed agent add/block + spin
__device__ __forceinline__ void gbar(unsigned* __restrict__ bar, unsigned target, int t) {
  asm volatile("s_waitcnt vmcnt(0)" ::: "memory");   // our bypass stores are globally visible
  __syncthreads();
  if (t == 0) {
    __hip_atomic_fetch_add(bar, 1u, __ATOMIC_RELAXED, __HIP_MEMORY_SCOPE_AGENT);
    while (__hip_atomic_load(bar, __ATOMIC_RELAXED, __HIP_MEMORY_SCOPE_AGENT) < target)
      __builtin_amdgcn_s_sleep(8);
  }
  __syncthreads();
}

// ---------------- persistent fused loop + final ----------------
__global__ __launch_bounds__(256) void k_loop2(float* __restrict__ D,
                                               const float* __restrict__ DT,
                                               float* __restrict__ fvec,
                                               float* __restrict__ gvec,
                                               unsigned* __restrict__ bar) {
  __shared__ float vs[N_PTS];
  const int t = threadIdx.x;
  const int l = t & 63, w = t >> 6;
  const int NBLK = gridDim.x;
  const int TW = NBLK * 4;
  const int W = blockIdx.x * 4 + w;
  unsigned target = 0;

  for (int it = 0; it < 30; ++it) {
    stage_vec(vs, fvec, t);
    __syncthreads();
    for (int c = W; c < N_PTS; c += TW) {
      float g = lse_row_lds(DT + (size_t)c * N_PTS, vs, l);
      if (l == 0) __hip_atomic_store(&gvec[c], g, __ATOMIC_RELAXED, __HIP_MEMORY_SCOPE_AGENT);
    }
    target += NBLK; gbar(bar, target, t);

    stage_vec(vs, gvec, t);
    __syncthreads();
    for (int r = W; r < N_PTS; r += TW) {
      float f = lse_row_lds(D + (size_t)r * N_PTS, vs, l);
      if (l == 0) __hip_atomic_store(&fvec[r], f, __ATOMIC_RELAXED, __HIP_MEMORY_SCOPE_AGENT);
    }
    target += NBLK; gbar(bar, target, t);
  }

  // final: P = exp2(0.1*(f_i + g_j - D_ij)) in place (gvec staged in vs)
  stage_vec(vs, gvec, t);
  __syncthreads();
  for (int r = W; r < N_PTS; r += TW) {
    float fi = __hip_atomic_load(&fvec[r], __ATOMIC_RELAXED, __HIP_MEMORY_SCOPE_AGENT);
    float* rp = D + (size_t)r * N_PTS;
#pragma unroll 4
    for (int k = 0; k < 16; ++k) {
      int j = l * 4 + k * 256;
      float4 d = *(const float4*)(rp + j);
      d.x = exp2f(0.1f * (fi + vs[j + 0] - d.x));
      d.y = exp2f(0.1f * (fi + vs[j + 1] - d.y));
      d.z = exp2f(0.1f * (fi + vs[j + 2] - d.z));
      d.w = exp2f(0.1f * (fi + vs[j + 3] - d.w));
      *(float4*)(rp + j) = d;
    }
  }
}

// ---------------- fallback path (ws too small): gather colpass + sweeps ----------------
__global__ __launch_bounds__(256) void k_sweep(const float* __restrict__ Mrow,
                                               const float* __restrict__ vin,
                                               float* __restrict__ vout) {
  const int l = threadIdx.x & 63;
  const int row = blockIdx.x * 4 + (threadIdx.x >> 6);
  float r = lse_row4096(Mrow + (size_t)row * N_PTS, vin, l);
  if (l == 0) vout[row] = r;
}

__global__ __launch_bounds__(1024) void k_colpass(const float* __restrict__ D,
                                                  const float* __restrict__ fvec,
                                                  float* __restrict__ gvec) {
  __shared__ float fs[N_PTS];
  __shared__ float4 MS[16][4][2];
  const int t = threadIdx.x;
  *(float4*)(fs + t * 4) = *(const float4*)(fvec + t * 4);
  __syncthreads();
  const int c4 = t & 3;
  const int rp = t >> 2;
  const float* base = D + blockIdx.x * 16 + c4 * 4;
  float4 M = make_float4(NEG_BIG, NEG_BIG, NEG_BIG, NEG_BIG);
  float4 S = make_float4(0.f, 0.f, 0.f, 0.f);
#pragma unroll
  for (int h = 0; h < 2; ++h) {
    float4 v[8];
#pragma unroll
    for (int qq = 0; qq < 8; ++qq) {
      int r = rp + (h * 8 + qq) * 256;
      float4 d = *(const float4*)(base + (size_t)r * N_PTS);
      float fr = fs[r];
      v[qq] = make_float4(fr - d.x, fr - d.y, fr - d.z, fr - d.w);
    }
    float4 Mc = f4max(f4max(f4max(v[0], v[1]), f4max(v[2], v[3])),
                      f4max(f4max(v[4], v[5]), f4max(v[6], v[7])));
    float4 Mn = f4max(M, Mc);
    float4 s;
    s.x = S.x * exp2f(M.x - Mn.x);
    s.y = S.y * exp2f(M.y - Mn.y);
    s.z = S.z * exp2f(M.z - Mn.z);
    s.w = S.w * exp2f(M.w - Mn.w);
#pragma unroll
    for (int qq = 0; qq < 8; ++qq) {
      s.x += exp2f(v[qq].x - Mn.x);
      s.y += exp2f(v[qq].y - Mn.y);
      s.z += exp2f(v[qq].z - Mn.z);
      s.w += exp2f(v[qq].w - Mn.w);
    }
    M = Mn; S = s;
  }
#pragma unroll
  for (int off = 4; off <= 32; off <<= 1) {
    float4 M2, S2;
    M2.x = __shfl_xor(M.x, off); M2.y = __shfl_xor(M.y, off);
    M2.z = __shfl_xor(M.z, off); M2.w = __shfl_xor(M.w, off);
    S2.x = __shfl_xor(S.x, off); S2.y = __shfl_xor(S.y, off);
    S2.z = __shfl_xor(S.z, off); S2.w = __shfl_xor(S.w, off);
    msmerge(M, S, M2, S2);
  }
  const int wv = t >> 6, l = t & 63;
  if (l < 4) { MS[wv][l][0] = M; MS[wv][l][1] = S; }
  __syncthreads();
  if (t < 4) {
    float4 M0 = MS[0][t][0], S0 = MS[0][t][1];
#pragma unroll
    for (int w = 1; w < 16; ++w) msmerge(M0, S0, MS[w][t][0], MS[w][t][1]);
    float4 g;
    g.x = 12.0f - M0.x - log2f(S0.x);
    g.y = 12.0f - M0.y - log2f(S0.y);
    g.z = 12.0f - M0.z - log2f(S0.z);
    g.w = 12.0f - M0.w - log2f(S0.w);
    *(float4*)(gvec + blockIdx.x * 16 + t * 4) = g;
  }
}

__global__ __launch_bounds__(256) void k_final(float* __restrict__ D,
                                               const float* __restrict__ fvec,
                                               const float* __restrict__ gvec) {
  size_t idx = ((size_t)blockIdx.x * 256 + threadIdx.x) * 8;
  int i = (int)(idx >> 12);
  int j = (int)(idx & (N_PTS - 1));
  float fi = fvec[i];
#pragma unroll
  for (int h = 0; h < 2; ++h) {
    float4 d  = *(float4*)(D + idx + h * 4);
    float4 g4 = *(const float4*)(gvec + j + h * 4);
    d.x = exp2f(0.1f * (fi + g4.x - d.x));
    d.y = exp2f(0.1f * (fi + g4.y - d.y));
    d.z = exp2f(0.1f * (fi + g4.z - d.z));
    d.w = exp2f(0.1f * (fi + g4.w - d.w));
    *(float4*)(D + idx + h * 4) = d;
  }
}

__global__ __launch_bounds__(256) void k_gemm(const float* __restrict__ A,
                                              const float* __restrict__ B,
                                              float* __restrict__ D) {
  __shared__ float As[16][132];
  __shared__ float Bs[16][132];
  const int t  = threadIdx.x;
  const int tx = t & 15, ty = t >> 4;
  const int row0 = blockIdx.y * 128, col0 = blockIdx.x * 128;
  float acc[8][8];
#pragma unroll
  for (int i = 0; i < 8; ++i)
#pragma unroll
    for (int j = 0; j < 8; ++j) acc[i][j] = 0.f;
  for (int k0 = 0; k0 < DIMK; k0 += 16) {
#pragma unroll
    for (int s2 = 0; s2 < 2; ++s2) {
      int f4i = t + s2 * 256;
      int r   = f4i >> 2;
      int kp  = (f4i & 3) << 2;
      float4 a4 = *(const float4*)(A + (size_t)(row0 + r) * DIMK + k0 + kp);
      float4 b4 = *(const float4*)(B + (size_t)(col0 + r) * DIMK + k0 + kp);
      As[kp + 0][r] = a4.x; As[kp + 1][r] = a4.y; As[kp + 2][r] = a4.z; As[kp + 3][r] = a4.w;
      Bs[kp + 0][r] = b4.x; Bs[kp + 1][r] = b4.y; Bs[kp + 2][r] = b4.z; Bs[kp + 3][r] = b4.w;
    }
    __syncthreads();
#pragma unroll
    for (int kk = 0; kk < 16; ++kk) {
      float a[8], b[8];
      *(float4*)(a)     = *(const float4*)(&As[kk][ty * 4]);
      *(float4*)(a + 4) = *(const float4*)(&As[kk][64 + ty * 4]);
      *(float4*)(b)     = *(const float4*)(&Bs[kk][tx * 4]);
      *(float4*)(b + 4) = *(const float4*)(&Bs[kk][64 + tx * 4]);
#pragma unroll
      for (int i = 0; i < 8; ++i)
#pragma unroll
        for (int j = 0; j < 8; ++j) acc[i][j] = fmaf(a[i], b[j], acc[i][j]);
    }
    __syncthreads();
  }
#pragma unroll
  for (int i = 0; i < 8; ++i) {
    int r = row0 + ((i < 4) ? (ty * 4 + i) : (64 + ty * 4 + (i - 4)));
    float* out = D + (size_t)r * N_PTS + col0;
    float4 o1, o2;
    o1.x = -TWO_S * acc[i][0]; o1.y = -TWO_S * acc[i][1];
    o1.z = -TWO_S * acc[i][2]; o1.w = -TWO_S * acc[i][3];
    o2.x = -TWO_S * acc[i][4]; o2.y = -TWO_S * acc[i][5];
    o2.z = -TWO_S * acc[i][6]; o2.w = -TWO_S * acc[i][7];
    *(float4*)(out + tx * 4)      = o1;
    *(float4*)(out + 64 + tx * 4) = o2;
  }
}

extern "C" void kernel_launch(void* const* d_in, const int* in_sizes, int n_in,
                              void* d_out, int out_size, void* d_ws, size_t ws_size,
                              hipStream_t stream) {
  const float* Xs = (const float*)d_in[0];
  const float* Xt = (const float*)d_in[1];
  float* D   = (float*)d_out;
  char* wsb  = (char*)d_ws;
  float* fvec = (float*)wsb;
  float* gvec = fvec + N_PTS;

  const size_t halfElems = (size_t)N_PTS * DIMK;
  const size_t offHalves = 32768;
  _Float16* Ah = (_Float16*)(wsb + offHalves);
  _Float16* Al = Ah + halfElems;
  _Float16* Bh = Al + halfElems;
  _Float16* Bl = Bh + halfElems;
  float* DT = (float*)(wsb + offHalves + 4 * halfElems * sizeof(_Float16));
  const size_t needHalves = offHalves + 4 * halfElems * sizeof(_Float16);
  const size_t offBar     = needHalves + (size_t)N_PTS * N_PTS * sizeof(float);
  const size_t needFull   = offBar + 1024;
  unsigned* bar = (unsigned*)(wsb + offBar);
  const bool haveH = ws_size >= needHalves;
  const bool haveT = ws_size >= needFull;

  k_prep<<<1024, 256, 0, stream>>>(Xs, fvec, haveT ? bar : nullptr);
  if (haveH) {
    k_convert<<<2048, 256, 0, stream>>>(Xs, Ah, Al);
    k_convert<<<2048, 256, 0, stream>>>(Xt, Bh, Bl);
    k_gemm_mfma<<<dim3(32, 32), 256, 0, stream>>>(Ah, Al, Bh, Bl, D, haveT ? DT : nullptr);
  } else {
    k_gemm<<<dim3(32, 32), 256, 0, stream>>>(Xs, Xt, D);
  }

  if (haveT) {
    int mb = 0;
    if (hipOccupancyMaxActiveBlocksPerMultiprocessor(&mb, (const void*)k_loop2, 256, 0) != hipSuccess || mb < 1)
      mb = 1;
    int NB = mb * 256;
    if (NB > 1024) NB = 1024;
    void* args[] = {(void*)&D, (void*)&DT, (void*)&fvec, (void*)&gvec, (void*)&bar};
    hipLaunchCooperativeKernel((const void*)k_loop2, dim3(NB), dim3(256), args, 0, stream);
  } else {
    for (int it = 0; it < 30; ++it) {
      k_colpass<<<256, 1024, 0, stream>>>(D, fvec, gvec);
      k_sweep<<<1024, 256, 0, stream>>>(D, gvec, fvec);
    }
    k_final<<<8192, 256, 0, stream>>>(D, fvec, gvec);
  }
}

// Round 8
// 989.337 us; speedup vs baseline: 2.9198x; 1.8106x over previous
//
#include <hip/hip_runtime.h>
#include <cstddef>
#include <cstdint>

#define N_PTS 4096
#define DIMK 1024

typedef _Float16 half8 __attribute__((ext_vector_type(8)));
typedef float floatx4 __attribute__((ext_vector_type(4)));

static constexpr float S_SCALE = 144.26950408889634f;   // 100*log2(e)
static constexpr float TWO_S   = 288.53900817779268f;   // 200*log2(e)
static constexpr float NEG_BIG = -3.4e38f;

// ws layout (bytes):
//   [0, 16K)        fvec (f~2s, shifted/gauged)   [16K, 32K) gvec
//   [32K, +32M)     Ah, Al, Bh, Bl (fp16 hi/lo splits; 8 MB each)
//   [then, +64M)    DT (transposed D for coalesced col-sweeps)
// Shifted/gauged coords: D2 = -2*S*x.y ; f2s_0 = S*(1024 - ||x_i||^2);
// f2s+g2s-D2 equals the reference's f+g-C exactly (gauge cancels).
// Round-8: multi-launch structure (964 us champion) + LDS-staged vin in the
// sweeps (VGPR 128->~64 live for vin, more waves/SIMD) + final fused into the
// 30th row sweep. All arithmetic bitwise-identical to round 4.

__device__ __forceinline__ float4 f4max(float4 a, float4 b) {
  return make_float4(fmaxf(a.x, b.x), fmaxf(a.y, b.y), fmaxf(a.z, b.z), fmaxf(a.w, b.w));
}
__device__ __forceinline__ void msmerge(float4& M, float4& S, const float4 M2, const float4 S2) {
  float4 Mn = f4max(M, M2);
  S.x = S.x * exp2f(M.x - Mn.x) + S2.x * exp2f(M2.x - Mn.x);
  S.y = S.y * exp2f(M.y - Mn.y) + S2.y * exp2f(M2.y - Mn.y);
  S.z = S.z * exp2f(M.z - Mn.z) + S2.z * exp2f(M2.z - Mn.z);
  S.w = S.w * exp2f(M.w - Mn.w) + S2.w * exp2f(M2.w - Mn.w);
  M = Mn;
}

// ---------------- prep: f~2s init = S*(1024 - ||Xs_i||^2) ----------------
__global__ __launch_bounds__(256) void k_prep(const float* __restrict__ Xs,
                                              float* __restrict__ fvec) {
  int row  = blockIdx.x * 4 + (threadIdx.x >> 6);
  int lane = threadIdx.x & 63;
  const float* src = Xs + (size_t)row * DIMK;
  float s = 0.f;
#pragma unroll
  for (int r = 0; r < 4; ++r) {
    float4 a = *(const float4*)(src + lane * 4 + r * 256);
    s += a.x * a.x + a.y * a.y + a.z * a.z + a.w * a.w;
  }
#pragma unroll
  for (int off = 32; off; off >>= 1) s += __shfl_xor(s, off);
  if (lane == 0) fvec[row] = (1024.0f - s) * S_SCALE;
}

// ---------------- convert: fp32 -> (hi, lo) fp16 split ----------------
__global__ __launch_bounds__(256) void k_convert(const float* __restrict__ X,
                                                 _Float16* __restrict__ H,
                                                 _Float16* __restrict__ L) {
  size_t i8 = ((size_t)blockIdx.x * 256 + threadIdx.x) * 8;
  float4 a = *(const float4*)(X + i8);
  float4 b = *(const float4*)(X + i8 + 4);
  float v[8] = {a.x, a.y, a.z, a.w, b.x, b.y, b.z, b.w};
  half8 h, l;
#pragma unroll
  for (int q = 0; q < 8; ++q) {
    _Float16 hh = (_Float16)v[q];
    h[q] = hh;
    l[q] = (_Float16)(v[q] - (float)hh);
  }
  *(half8*)(H + i8) = h;
  *(half8*)(L + i8) = l;
}

// ---------------- MFMA split-fp16 GEMM: D = -2S * (Ah+Al).(Bh+Bl)^T ----------------
// dot = hh + hl + lh (lo*lo dropped: < 2^-22 relative). Writes D and DT.
__global__ __launch_bounds__(256) void k_gemm_mfma(const _Float16* __restrict__ Ah,
                                                   const _Float16* __restrict__ Al,
                                                   const _Float16* __restrict__ Bh,
                                                   const _Float16* __restrict__ Bl,
                                                   float* __restrict__ D,
                                                   float* __restrict__ DT) {
  __shared__ __align__(16) _Float16 Ahs[128 * 32];
  __shared__ __align__(16) _Float16 Als[128 * 32];
  __shared__ __align__(16) _Float16 Bhs[128 * 32];
  __shared__ __align__(16) _Float16 Bls[128 * 32];
  const int t    = threadIdx.x;
  const int lane = t & 63, wave = t >> 6;
  const int wm = wave >> 1, wn = wave & 1;
  const int lm = lane & 15, q = lane >> 4;
  const int row0 = blockIdx.y * 128, col0 = blockIdx.x * 128;

  floatx4 acc[4][4];
#pragma unroll
  for (int i = 0; i < 4; ++i)
#pragma unroll
    for (int j = 0; j < 4; ++j) acc[i][j] = (floatx4){0.f, 0.f, 0.f, 0.f};

  const int r0 = t >> 2, p0 = t & 3;
  const int r1 = 64 + r0;

  for (int k0 = 0; k0 < DIMK; k0 += 32) {
    size_t ga0 = (size_t)(row0 + r0) * DIMK + k0 + p0 * 8;
    size_t ga1 = (size_t)(row0 + r1) * DIMK + k0 + p0 * 8;
    size_t gb0 = (size_t)(col0 + r0) * DIMK + k0 + p0 * 8;
    size_t gb1 = (size_t)(col0 + r1) * DIMK + k0 + p0 * 8;
    half8 vah0 = *(const half8*)(Ah + ga0);
    half8 vah1 = *(const half8*)(Ah + ga1);
    half8 val0 = *(const half8*)(Al + ga0);
    half8 val1 = *(const half8*)(Al + ga1);
    half8 vbh0 = *(const half8*)(Bh + gb0);
    half8 vbh1 = *(const half8*)(Bh + gb1);
    half8 vbl0 = *(const half8*)(Bl + gb0);
    half8 vbl1 = *(const half8*)(Bl + gb1);
    __syncthreads();
    ((half8*)Ahs)[t] = vah0; ((half8*)Ahs)[t + 256] = vah1;
    ((half8*)Als)[t] = val0; ((half8*)Als)[t + 256] = val1;
    ((half8*)Bhs)[t] = vbh0; ((half8*)Bhs)[t + 256] = vbh1;
    ((half8*)Bls)[t] = vbl0; ((half8*)Bls)[t + 256] = vbl1;
    __syncthreads();

    half8 afh[4], afl[4], bfh[4], bfl[4];
#pragma unroll
    for (int i = 0; i < 4; ++i) {
      int ar = (wm * 64 + i * 16 + lm) * 32 + q * 8;
      int br = (wn * 64 + i * 16 + lm) * 32 + q * 8;
      afh[i] = *(const half8*)(Ahs + ar);
      afl[i] = *(const half8*)(Als + ar);
      bfh[i] = *(const half8*)(Bhs + br);
      bfl[i] = *(const half8*)(Bls + br);
    }
#pragma unroll
    for (int i = 0; i < 4; ++i)
#pragma unroll
      for (int j = 0; j < 4; ++j) {
        acc[i][j] = __builtin_amdgcn_mfma_f32_16x16x32_f16(afh[i], bfh[j], acc[i][j], 0, 0, 0);
        acc[i][j] = __builtin_amdgcn_mfma_f32_16x16x32_f16(afh[i], bfl[j], acc[i][j], 0, 0, 0);
        acc[i][j] = __builtin_amdgcn_mfma_f32_16x16x32_f16(afl[i], bfh[j], acc[i][j], 0, 0, 0);
      }
  }

  // epilogue: C/D layout col=lane&15, row=quad*4+reg
#pragma unroll
  for (int i = 0; i < 4; ++i) {
    int mbase = row0 + wm * 64 + i * 16 + q * 4;
#pragma unroll
    for (int j = 0; j < 4; ++j) {
      int n = col0 + wn * 64 + j * 16 + lm;
      float vals[4];
#pragma unroll
      for (int r = 0; r < 4; ++r) {
        float vv = -TWO_S * acc[i][j][r];
        vals[r] = vv;
        D[(size_t)(mbase + r) * N_PTS + n] = vv;
      }
      if (DT) *(float4*)(DT + (size_t)n * N_PTS + mbase) = *(float4*)vals;
    }
  }
}

// ---------------- sweep v2: LDS-staged vin, one wave per row ----------------
// Arithmetic bitwise-identical to round-4 k_sweep (same chunk order, same
// butterfly); only the vin source (LDS instead of global) changed.
__global__ __launch_bounds__(256) void k_sweep2(const float* __restrict__ Mrow,
                                                const float* __restrict__ vin,
                                                float* __restrict__ vout) {
  __shared__ float vs[N_PTS];
  const int t = threadIdx.x;
  const int l = t & 63;
  const int row = blockIdx.x * 4 + (t >> 6);
#pragma unroll
  for (int k = 0; k < 4; ++k)
    *(float4*)(vs + t * 4 + k * 1024) = *(const float4*)(vin + t * 4 + k * 1024);
  __syncthreads();
  const float* rp_ = Mrow + (size_t)row * N_PTS;
  float4 dv[16];
#pragma unroll
  for (int k = 0; k < 16; ++k) dv[k] = *(const float4*)(rp_ + l * 4 + k * 256);
  float M = NEG_BIG, S = 0.f;
#pragma unroll
  for (int c = 0; c < 4; ++c) {
    float v[16];
#pragma unroll
    for (int q = 0; q < 4; ++q) {
      float4 d = dv[c * 4 + q];
      const float* gp = vs + l * 4 + (c * 4 + q) * 256;
      v[q * 4 + 0] = gp[0] - d.x; v[q * 4 + 1] = gp[1] - d.y;
      v[q * 4 + 2] = gp[2] - d.z; v[q * 4 + 3] = gp[3] - d.w;
    }
    float Mc = v[0];
#pragma unroll
    for (int q = 1; q < 16; ++q) Mc = fmaxf(Mc, v[q]);
    float Mn = fmaxf(M, Mc);
    float s = S * exp2f(M - Mn);
#pragma unroll
    for (int q = 0; q < 16; ++q) s += exp2f(v[q] - Mn);
    M = Mn; S = s;
  }
#pragma unroll
  for (int off = 32; off; off >>= 1) {
    float M2 = __shfl_xor(M, off);
    float S2 = __shfl_xor(S, off);
    float Mn = fmaxf(M, M2);
    S = S * exp2f(M - Mn) + S2 * exp2f(M2 - Mn);
    M = Mn;
  }
  if (l == 0) vout[row] = 12.0f - M - log2f(S);
}

// ---------------- sweep+final fused: 30th row sweep writes P in place ----------------
// f computed in all lanes (butterfly), then P = exp2(0.1*(f_i + g_j - D_ij))
// reusing the still-live dv registers. Values bitwise-identical to
// k_sweep2-then-k_final.
__global__ __launch_bounds__(256) void k_sweepF(float* __restrict__ D,
                                                const float* __restrict__ gvec) {
  __shared__ float vs[N_PTS];
  const int t = threadIdx.x;
  const int l = t & 63;
  const int row = blockIdx.x * 4 + (t >> 6);
#pragma unroll
  for (int k = 0; k < 4; ++k)
    *(float4*)(vs + t * 4 + k * 1024) = *(const float4*)(gvec + t * 4 + k * 1024);
  __syncthreads();
  float* rp_ = D + (size_t)row * N_PTS;
  float4 dv[16];
#pragma unroll
  for (int k = 0; k < 16; ++k) dv[k] = *(const float4*)(rp_ + l * 4 + k * 256);
  float M = NEG_BIG, S = 0.f;
#pragma unroll
  for (int c = 0; c < 4; ++c) {
    float v[16];
#pragma unroll
    for (int q = 0; q < 4; ++q) {
      float4 d = dv[c * 4 + q];
      const float* gp = vs + l * 4 + (c * 4 + q) * 256;
      v[q * 4 + 0] = gp[0] - d.x; v[q * 4 + 1] = gp[1] - d.y;
      v[q * 4 + 2] = gp[2] - d.z; v[q * 4 + 3] = gp[3] - d.w;
    }
    float Mc = v[0];
#pragma unroll
    for (int q = 1; q < 16; ++q) Mc = fmaxf(Mc, v[q]);
    float Mn = fmaxf(M, Mc);
    float s = S * exp2f(M - Mn);
#pragma unroll
    for (int q = 0; q < 16; ++q) s += exp2f(v[q] - Mn);
    M = Mn; S = s;
  }
#pragma unroll
  for (int off = 32; off; off >>= 1) {
    float M2 = __shfl_xor(M, off);
    float S2 = __shfl_xor(S, off);
    float Mn = fmaxf(M, M2);
    S = S * exp2f(M - Mn) + S2 * exp2f(M2 - Mn);
    M = Mn;
  }
  const float fi = 12.0f - M - log2f(S);
#pragma unroll
  for (int k = 0; k < 16; ++k) {
    int j = l * 4 + k * 256;
    float4 d = dv[k];
    const float* gp = vs + j;
    d.x = exp2f(0.1f * (fi + gp[0] - d.x));
    d.y = exp2f(0.1f * (fi + gp[1] - d.y));
    d.z = exp2f(0.1f * (fi + gp[2] - d.z));
    d.w = exp2f(0.1f * (fi + gp[3] - d.w));
    *(float4*)(rp_ + j) = d;
  }
}

// ---------------- fallback path (ws too small): old sweeps + colpass + final ----------------
__device__ __forceinline__ float lse_row4096(const float* __restrict__ rowp,
                                             const float* __restrict__ vin,
                                             int l) {
  float4 dv[16], gv[16];
#pragma unroll
  for (int k = 0; k < 16; ++k) dv[k] = *(const float4*)(rowp + l * 4 + k * 256);
#pragma unroll
  for (int k = 0; k < 16; ++k) gv[k] = *(const float4*)(vin + l * 4 + k * 256);
  float M = NEG_BIG, S = 0.f;
#pragma unroll
  for (int c = 0; c < 4; ++c) {
    float v[16];
#pragma unroll
    for (int q = 0; q < 4; ++q) {
      float4 d = dv[c * 4 + q], g = gv[c * 4 + q];
      v[q * 4 + 0] = g.x - d.x; v[q * 4 + 1] = g.y - d.y;
      v[q * 4 + 2] = g.z - d.z; v[q * 4 + 3] = g.w - d.w;
    }
    float Mc = v[0];
#pragma unroll
    for (int q = 1; q < 16; ++q) Mc = fmaxf(Mc, v[q]);
    float Mn = fmaxf(M, Mc);
    float s = S * exp2f(M - Mn);
#pragma unroll
    for (int q = 0; q < 16; ++q) s += exp2f(v[q] - Mn);
    M = Mn; S = s;
  }
#pragma unroll
  for (int off = 32; off; off >>= 1) {
    float M2 = __shfl_xor(M, off);
    float S2 = __shfl_xor(S, off);
    float Mn = fmaxf(M, M2);
    S = S * exp2f(M - Mn) + S2 * exp2f(M2 - Mn);
    M = Mn;
  }
  return 12.0f - M - log2f(S);
}

__global__ __launch_bounds__(256) void k_sweep(const float* __restrict__ Mrow,
                                               const float* __restrict__ vin,
                                               float* __restrict__ vout) {
  const int l = threadIdx.x & 63;
  const int row = blockIdx.x * 4 + (threadIdx.x >> 6);
  float r = lse_row4096(Mrow + (size_t)row * N_PTS, vin, l);
  if (l == 0) vout[row] = r;
}

__global__ __launch_bounds__(1024) void k_colpass(const float* __restrict__ D,
                                                  const float* __restrict__ fvec,
                                                  float* __restrict__ gvec) {
  __shared__ float fs[N_PTS];
  __shared__ float4 MS[16][4][2];
  const int t = threadIdx.x;
  *(float4*)(fs + t * 4) = *(const float4*)(fvec + t * 4);
  __syncthreads();
  const int c4 = t & 3;
  const int rp = t >> 2;
  const float* base = D + blockIdx.x * 16 + c4 * 4;
  float4 M = make_float4(NEG_BIG, NEG_BIG, NEG_BIG, NEG_BIG);
  float4 S = make_float4(0.f, 0.f, 0.f, 0.f);
#pragma unroll
  for (int h = 0; h < 2; ++h) {
    float4 v[8];
#pragma unroll
    for (int qq = 0; qq < 8; ++qq) {
      int r = rp + (h * 8 + qq) * 256;
      float4 d = *(const float4*)(base + (size_t)r * N_PTS);
      float fr = fs[r];
      v[qq] = make_float4(fr - d.x, fr - d.y, fr - d.z, fr - d.w);
    }
    float4 Mc = f4max(f4max(f4max(v[0], v[1]), f4max(v[2], v[3])),
                      f4max(f4max(v[4], v[5]), f4max(v[6], v[7])));
    float4 Mn = f4max(M, Mc);
    float4 s;
    s.x = S.x * exp2f(M.x - Mn.x);
    s.y = S.y * exp2f(M.y - Mn.y);
    s.z = S.z * exp2f(M.z - Mn.z);
    s.w = S.w * exp2f(M.w - Mn.w);
#pragma unroll
    for (int qq = 0; qq < 8; ++qq) {
      s.x += exp2f(v[qq].x - Mn.x);
      s.y += exp2f(v[qq].y - Mn.y);
      s.z += exp2f(v[qq].z - Mn.z);
      s.w += exp2f(v[qq].w - Mn.w);
    }
    M = Mn; S = s;
  }
#pragma unroll
  for (int off = 4; off <= 32; off <<= 1) {
    float4 M2, S2;
    M2.x = __shfl_xor(M.x, off); M2.y = __shfl_xor(M.y, off);
    M2.z = __shfl_xor(M.z, off); M2.w = __shfl_xor(M.w, off);
    S2.x = __shfl_xor(S.x, off); S2.y = __shfl_xor(S.y, off);
    S2.z = __shfl_xor(S.z, off); S2.w = __shfl_xor(S.w, off);
    msmerge(M, S, M2, S2);
  }
  const int wv = t >> 6, l = t & 63;
  if (l < 4) { MS[wv][l][0] = M; MS[wv][l][1] = S; }
  __syncthreads();
  if (t < 4) {
    float4 M0 = MS[0][t][0], S0 = MS[0][t][1];
#pragma unroll
    for (int w = 1; w < 16; ++w) msmerge(M0, S0, MS[w][t][0], MS[w][t][1]);
    float4 g;
    g.x = 12.0f - M0.x - log2f(S0.x);
    g.y = 12.0f - M0.y - log2f(S0.y);
    g.z = 12.0f - M0.z - log2f(S0.z);
    g.w = 12.0f - M0.w - log2f(S0.w);
    *(float4*)(gvec + blockIdx.x * 16 + t * 4) = g;
  }
}

__global__ __launch_bounds__(256) void k_final(float* __restrict__ D,
                                               const float* __restrict__ fvec,
                                               const float* __restrict__ gvec) {
  size_t idx = ((size_t)blockIdx.x * 256 + threadIdx.x) * 8;
  int i = (int)(idx >> 12);
  int j = (int)(idx & (N_PTS - 1));
  float fi = fvec[i];
#pragma unroll
  for (int h = 0; h < 2; ++h) {
    float4 d  = *(float4*)(D + idx + h * 4);
    float4 g4 = *(const float4*)(gvec + j + h * 4);
    d.x = exp2f(0.1f * (fi + g4.x - d.x));
    d.y = exp2f(0.1f * (fi + g4.y - d.y));
    d.z = exp2f(0.1f * (fi + g4.z - d.z));
    d.w = exp2f(0.1f * (fi + g4.w - d.w));
    *(float4*)(D + idx + h * 4) = d;
  }
}

__global__ __launch_bounds__(256) void k_gemm(const float* __restrict__ A,
                                              const float* __restrict__ B,
                                              float* __restrict__ D) {
  __shared__ float As[16][132];
  __shared__ float Bs[16][132];
  const int t  = threadIdx.x;
  const int tx = t & 15, ty = t >> 4;
  const int row0 = blockIdx.y * 128, col0 = blockIdx.x * 128;
  float acc[8][8];
#pragma unroll
  for (int i = 0; i < 8; ++i)
#pragma unroll
    for (int j = 0; j < 8; ++j) acc[i][j] = 0.f;
  for (int k0 = 0; k0 < DIMK; k0 += 16) {
#pragma unroll
    for (int s2 = 0; s2 < 2; ++s2) {
      int f4i = t + s2 * 256;
      int r   = f4i >> 2;
      int kp  = (f4i & 3) << 2;
      float4 a4 = *(const float4*)(A + (size_t)(row0 + r) * DIMK + k0 + kp);
      float4 b4 = *(const float4*)(B + (size_t)(col0 + r) * DIMK + k0 + kp);
      As[kp + 0][r] = a4.x; As[kp + 1][r] = a4.y; As[kp + 2][r] = a4.z; As[kp + 3][r] = a4.w;
      Bs[kp + 0][r] = b4.x; Bs[kp + 1][r] = b4.y; Bs[kp + 2][r] = b4.z; Bs[kp + 3][r] = b4.w;
    }
    __syncthreads();
#pragma unroll
    for (int kk = 0; kk < 16; ++kk) {
      float a[8], b[8];
      *(float4*)(a)     = *(const float4*)(&As[kk][ty * 4]);
      *(float4*)(a + 4) = *(const float4*)(&As[kk][64 + ty * 4]);
      *(float4*)(b)     = *(const float4*)(&Bs[kk][tx * 4]);
      *(float4*)(b + 4) = *(const float4*)(&Bs[kk][64 + tx * 4]);
#pragma unroll
      for (int i = 0; i < 8; ++i)
#pragma unroll
        for (int j = 0; j < 8; ++j) acc[i][j] = fmaf(a[i], b[j], acc[i][j]);
    }
    __syncthreads();
  }
#pragma unroll
  for (int i = 0; i < 8; ++i) {
    int r = row0 + ((i < 4) ? (ty * 4 + i) : (64 + ty * 4 + (i - 4)));
    float* out = D + (size_t)r * N_PTS + col0;
    float4 o1, o2;
    o1.x = -TWO_S * acc[i][0]; o1.y = -TWO_S * acc[i][1];
    o1.z = -TWO_S * acc[i][2]; o1.w = -TWO_S * acc[i][3];
    o2.x = -TWO_S * acc[i][4]; o2.y = -TWO_S * acc[i][5];
    o2.z = -TWO_S * acc[i][6]; o2.w = -TWO_S * acc[i][7];
    *(float4*)(out + tx * 4)      = o1;
    *(float4*)(out + 64 + tx * 4) = o2;
  }
}

extern "C" void kernel_launch(void* const* d_in, const int* in_sizes, int n_in,
                              void* d_out, int out_size, void* d_ws, size_t ws_size,
                              hipStream_t stream) {
  const float* Xs = (const float*)d_in[0];
  const float* Xt = (const float*)d_in[1];
  float* D   = (float*)d_out;
  char* wsb  = (char*)d_ws;
  float* fvec = (float*)wsb;
  float* gvec = fvec + N_PTS;

  const size_t halfElems = (size_t)N_PTS * DIMK;
  const size_t offHalves = 32768;
  _Float16* Ah = (_Float16*)(wsb + offHalves);
  _Float16* Al = Ah + halfElems;
  _Float16* Bh = Al + halfElems;
  _Float16* Bl = Bh + halfElems;
  float* DT = (float*)(wsb + offHalves + 4 * halfElems * sizeof(_Float16));
  const size_t needHalves = offHalves + 4 * halfElems * sizeof(_Float16);          // ~32.03 MB
  const size_t needFull   = needHalves + (size_t)N_PTS * N_PTS * sizeof(float);    // +64 MB
  const bool haveH = ws_size >= needHalves;
  const bool haveT = ws_size >= needFull;

  k_prep<<<1024, 256, 0, stream>>>(Xs, fvec);
  if (haveH) {
    k_convert<<<2048, 256, 0, stream>>>(Xs, Ah, Al);
    k_convert<<<2048, 256, 0, stream>>>(Xt, Bh, Bl);
    k_gemm_mfma<<<dim3(32, 32), 256, 0, stream>>>(Ah, Al, Bh, Bl, D, haveT ? DT : nullptr);
  } else {
    k_gemm<<<dim3(32, 32), 256, 0, stream>>>(Xs, Xt, D);
  }

  if (haveT) {
    for (int it = 0; it < 30; ++it) {
      k_sweep2<<<1024, 256, 0, stream>>>(DT, fvec, gvec);
      if (it < 29) k_sweep2<<<1024, 256, 0, stream>>>(D, gvec, fvec);
      else         k_sweepF<<<1024, 256, 0, stream>>>(D, gvec);
    }
  } else {
    for (int it = 0; it < 30; ++it) {
      k_colpass<<<256, 1024, 0, stream>>>(D, fvec, gvec);
      k_sweep<<<1024, 256, 0, stream>>>(D, gvec, fvec);
    }
    k_final<<<8192, 256, 0, stream>>>(D, fvec, gvec);
  }
}